// Round 8
// baseline (50.731 us; speedup 1.0000x reference)
//
#include <hip/hip_runtime.h>

// Grouped conv 3x3 SAME, NHWC fp32 -> bf16 MFMA, LDS 5-plane ring h-walk.
// vs R6: (1) __syncthreads -> raw "lgkmcnt(0); s_barrier" (no vmcnt(0) drain:
// in-flight global loads/stores legally cross the barrier; LDS ordering only),
// (2) plain stores instead of NT (NT inflated HBM writes 100->145 MB).
#define NG 8
#define PC 32
#define FC 64
#define HH 56
#define WW 56
#define CIN 256
#define COUT 512
#define NB 16
#define SL 66              // w slots: w_in = slot-1 in [-1,64]
#define PLANE (SL * 64)    // 4224 B per plane (66 slots * 32ch * 2B)
#define NPL 5              // ring planes
#define HCH 7              // h rows per block

typedef __bf16 bf16x8 __attribute__((ext_vector_type(8)));
typedef float f32x4 __attribute__((ext_vector_type(4)));

// LDS-ordering-only barrier: ds ops drained, global loads/stores stay in flight
static __device__ __forceinline__ void lds_barrier() {
    asm volatile("s_waitcnt lgkmcnt(0)\n\ts_barrier" ::: "memory");
}

// kernels [g][kh][kw][p][f] f32 -> [g][tap][f][p] bf16
__global__ void cvt_w_kernel(const float* __restrict__ in,
                             __bf16* __restrict__ outb) {
    int id = blockIdx.x * blockDim.x + threadIdx.x;
    if (id >= NG * 9 * FC * PC) return;
    const int p = id & (PC - 1);
    int rest = id >> 5;
    const int f = rest & (FC - 1);
    rest >>= 6;
    const int t = rest % 9;
    const int g = rest / 9;
    outb[id] = (__bf16)in[(((size_t)(g * 9 + t)) * PC + p) * FC + f];
}

static __device__ __forceinline__ bf16x8 cvt8(f32x4 a, f32x4 b) {
    bf16x8 r;
    r[0] = (__bf16)a[0]; r[1] = (__bf16)a[1]; r[2] = (__bf16)a[2]; r[3] = (__bf16)a[3];
    r[4] = (__bf16)b[0]; r[5] = (__bf16)b[1]; r[6] = (__bf16)b[2]; r[7] = (__bf16)b[3];
    return r;
}

static __device__ __forceinline__ int swz(int loc) {
    return loc ^ (((loc >> 7) & 3) << 4);
}

__global__ __launch_bounds__(256, 4)
void groupconv_ring_kernel(const float* __restrict__ x,
                           const __bf16* __restrict__ wb,
                           const float* __restrict__ bias,
                           float* __restrict__ out) {
    const int b   = blockIdx.x;
    const int g   = b & 7;
    const int hcb = (b >> 3) & 7;
    const int n   = b >> 6;
    const int h0  = hcb * HCH;

    const int tid  = threadIdx.x;
    const int wave = tid >> 6;
    const int lane = tid & 63;
    const int lo = lane & 15;
    const int hi = lane >> 4;
    const int p0 = hi * 8;
    const int fm  = (wave >> 1) * 32;   // filter half
    const int wnb = (wave & 1) * 32;    // w half

    __shared__ __align__(16) unsigned char xsb[NPL * PLANE];  // 21120 B

    // ---- stationary weight frags (A-operand: M=filters) ----
    bf16x8 bfr[9][2];
    {
        const __bf16* wgp = wb + ((size_t)g * 9 * FC) * PC;
#pragma unroll
        for (int t = 0; t < 9; ++t)
#pragma unroll
            for (int mi = 0; mi < 2; ++mi)
                bfr[t][mi] = *reinterpret_cast<const bf16x8*>(
                    wgp + ((size_t)t * FC + (fm + mi * 16 + lo)) * PC + p0);
    }

    // ---- zero-fill constant-zero slots (57..65) of all planes, once ----
    if (tid < 180) {
        const int q  = tid & 3;
        const int sq = tid >> 2;        // 0..44
        const int pl = sq / 9;
        const int s  = 57 + (sq % 9);
        *reinterpret_cast<bf16x8*>(xsb + pl * PLANE + swz(s * 64 + q * 16)) =
            (bf16x8)(__bf16)0.f;
    }

    // ---- stage mapping: thread -> (slot, ch-octet), slots 0..56 active ----
    const int sq_q = tid & 3;
    const int sq_s = tid >> 2;          // 0..63
    const bool st_act = sq_s < 57;
    const int w_in = sq_s - 1;
    const bool w_ok = st_act && ((unsigned)w_in < WW);
    const float* xq = x + ((size_t)n * HH * WW) * CIN + g * PC + sq_q * 8;
    const int wloc = swz(sq_s * 64 + sq_q * 16);

    // ---- prologue: rows h0-1..h0+1 -> planes 0..2 ----
    f32x4 pa[3], pb[3];
#pragma unroll
    for (int rr = 0; rr < 3; ++rr) {
        const int r = h0 - 1 + rr;
        pa[rr] = (f32x4)0.f; pb[rr] = (f32x4)0.f;
        if (w_ok && (unsigned)r < HH) {
            const float* p = xq + ((size_t)r * WW + w_in) * CIN;
            pa[rr] = *reinterpret_cast<const f32x4*>(p);
            pb[rr] = *reinterpret_cast<const f32x4*>(p + 4);
        }
    }
#pragma unroll
    for (int rr = 0; rr < 3; ++rr)
        if (st_act)
            *reinterpret_cast<bf16x8*>(xsb + rr * PLANE + wloc) = cvt8(pa[rr], pb[rr]);

    // reg-prefetch row h0+2
    f32x4 sa = (f32x4)0.f, sb = (f32x4)0.f;
    {
        const int r = h0 + 2;
        if (w_ok && (unsigned)r < HH) {
            const float* p = xq + ((size_t)r * WW + w_in) * CIN;
            sa = *reinterpret_cast<const f32x4*>(p);
            sb = *reinterpret_cast<const f32x4*>(p + 4);
        }
    }

    float4 bvv[2];
#pragma unroll
    for (int mi = 0; mi < 2; ++mi)
        bvv[mi] = *reinterpret_cast<const float4*>(bias + g * FC + fm + mi * 16 + hi * 4);

    float* const outg = out + ((size_t)n * HH * WW) * COUT + g * FC;

#pragma unroll
    for (int i = 0; i < HCH; ++i) {
        const int h = h0 + i;

        // write staged row h+2 -> plane (i+3)%5  (before barrier)
        if (st_act)
            *reinterpret_cast<bf16x8*>(xsb + ((i + 3) % NPL) * PLANE + wloc) = cvt8(sa, sb);

        // issue loads for row h+3 (consumed next iter; stays in flight across barrier)
        if (i + 1 < HCH) {
            const int r = h + 3;
            sa = (f32x4)0.f; sb = (f32x4)0.f;
            if (w_ok && (unsigned)r < HH) {
                const float* p = xq + ((size_t)r * WW + w_in) * CIN;
                sa = *reinterpret_cast<const f32x4*>(p);
                sb = *reinterpret_cast<const f32x4*>(p + 4);
            }
        }

        lds_barrier();   // LDS ordering only — no vmcnt(0) drain

        // compute row h: planes (i+kh)%5, 18 ds_read + 36 MFMA
        f32x4 acc[2][2];
#pragma unroll
        for (int mi = 0; mi < 2; ++mi)
#pragma unroll
            for (int nj = 0; nj < 2; ++nj) acc[mi][nj] = (f32x4)0.f;

#pragma unroll
        for (int kh = 0; kh < 3; ++kh) {
            const unsigned char* plb = xsb + ((i + kh) % NPL) * PLANE;
#pragma unroll
            for (int kw = 0; kw < 3; ++kw) {
                const int t = kh * 3 + kw;
                bf16x8 bx[2];
#pragma unroll
                for (int nj = 0; nj < 2; ++nj) {
                    const int s = wnb + nj * 16 + lo + kw;
                    bx[nj] = *reinterpret_cast<const bf16x8*>(plb + swz(s * 64 + hi * 16));
                }
#pragma unroll
                for (int mi = 0; mi < 2; ++mi)
#pragma unroll
                    for (int nj = 0; nj < 2; ++nj)
                        acc[mi][nj] = __builtin_amdgcn_mfma_f32_16x16x32_bf16(
                            bfr[t][mi], bx[nj], acc[mi][nj], 0, 0, 0);
            }
        }

        // store row h (plain stores: L2 write-combining merges lines)
        float* const orow = outg + ((size_t)h * WW) * COUT;
#pragma unroll
        for (int mi = 0; mi < 2; ++mi) {
            const int f0 = fm + mi * 16 + hi * 4;
#pragma unroll
            for (int nj = 0; nj < 2; ++nj) {
                const int w = wnb + nj * 16 + lo;
                if (w < WW) {
                    f32x4 o = acc[mi][nj];
                    o[0] += bvv[mi].x; o[1] += bvv[mi].y;
                    o[2] += bvv[mi].z; o[3] += bvv[mi].w;
                    *reinterpret_cast<f32x4*>(orow + (size_t)w * COUT + f0) = o;
                }
            }
        }

        // barrier before next iter's ds_write overwrites a retired plane is NOT
        // needed: ring distance analysis (5 planes, 1 barrier/iter) keeps the
        // write plane disjoint from every concurrent reader's planes.
    }
}

// ---------------- fallback fp32 kernel ----------------
__global__ __launch_bounds__(256, 2)
void groupconv_f32_kernel(const float* __restrict__ x,
                          const float* __restrict__ krn,
                          const float* __restrict__ bias,
                          float* __restrict__ out) {
    const int b  = blockIdx.x;
    const int g  = b % NG;
    const int h  = (b / NG) % HH;
    const int n  = b / (NG * HH);
    const int tid = threadIdx.x;
    const int f   = tid & 63;
    const int wq  = tid >> 6;
    const int wbase = wq * 14;

    float acc[14];
#pragma unroll
    for (int i = 0; i < 14; ++i) acc[i] = 0.f;

    const float* kg = krn + (size_t)g * (9 * PC * FC);

    for (int kh = 0; kh < 3; ++kh) {
        const int hin = h + kh - 1;
        if (hin < 0 || hin >= HH) continue;
        const float* xrow = x + (((size_t)n * HH + hin) * WW) * CIN + g * PC;
        for (int pq = 0; pq < 8; ++pq) {
            float4 xv[16];
#pragma unroll
            for (int t = 0; t < 16; ++t) {
                const int win = wbase + t - 1;
                if (win >= 0 && win < WW)
                    xv[t] = *reinterpret_cast<const float4*>(xrow + (size_t)win * CIN + pq * 4);
                else
                    xv[t] = make_float4(0.f, 0.f, 0.f, 0.f);
            }
#pragma unroll
            for (int kw = 0; kw < 3; ++kw) {
                const float* kp = kg + ((kh * 3 + kw) * PC + pq * 4) * FC + f;
                const float w0 = kp[0 * FC], w1 = kp[1 * FC], w2 = kp[2 * FC], w3 = kp[3 * FC];
#pragma unroll
                for (int i = 0; i < 14; ++i) {
                    const float4 xt = xv[i + kw];
                    acc[i] = fmaf(xt.x, w0, acc[i]);
                    acc[i] = fmaf(xt.y, w1, acc[i]);
                    acc[i] = fmaf(xt.z, w2, acc[i]);
                    acc[i] = fmaf(xt.w, w3, acc[i]);
                }
            }
        }
    }

    const float bv = bias[g * FC + f];
    float* orow = out + (((size_t)n * HH + h) * WW + wbase) * COUT + g * FC + f;
#pragma unroll
    for (int i = 0; i < 14; ++i) orow[(size_t)i * COUT] = acc[i] + bv;
}

// ---------------- launcher ----------------
extern "C" void kernel_launch(void* const* d_in, const int* in_sizes, int n_in,
                              void* d_out, int out_size, void* d_ws, size_t ws_size,
                              hipStream_t stream) {
    const float* x    = (const float*)d_in[0];
    const float* krn  = (const float*)d_in[1];
    const float* bias = (const float*)d_in[2];
    float* out = (float*)d_out;

    const size_t w_elems = (size_t)NG * 9 * FC * PC;
    if (ws_size < w_elems * sizeof(__bf16)) {
        groupconv_f32_kernel<<<NB * HH * NG, 256, 0, stream>>>(x, krn, bias, out);
        return;
    }

    __bf16* wbuf = (__bf16*)d_ws;
    cvt_w_kernel<<<(int)((w_elems + 255) / 256), 256, 0, stream>>>(krn, wbuf);

    const int blocks = NB * 8 * NG;  // n * hchunks * g = 1024
    groupconv_ring_kernel<<<blocks, 256, 0, stream>>>(x, wbuf, bias, out);
}